// Round 1
// baseline (26604.178 us; speedup 1.0000x reference)
//
#include <hip/hip_runtime.h>
#include <math.h>

// Problem constants
#define BB 8
#define SS 512
#define DD 768
#define HH 12
#define LL 12
#define DHD 64
#define DFF 3072
#define VV 40478
#define MM (BB*SS)   // 4096 rows

// ---------------------------------------------------------------------------
// Embedding: x[b,s,:] = we[tok[b,s],:] + we[V+s,:]
// ---------------------------------------------------------------------------
__global__ __launch_bounds__(256) void embed_kernel(
    const int* __restrict__ tokens, const float* __restrict__ we,
    float* __restrict__ x)
{
    int i = blockIdx.x;          // 0..4095 (b*512+s)
    int s = i & (SS - 1);
    int tok = tokens[i];
    const float* wt = we + (size_t)tok * DD;
    const float* wp = we + (size_t)(VV + s) * DD;
    float* xr = x + (size_t)i * DD;
    for (int d = threadIdx.x; d < DD; d += 256)
        xr[d] = wt[d] + wp[d];
}

// ---------------------------------------------------------------------------
// Tiled fp32 GEMM: C[M,N] = A[M,K] @ B[K,N] + bias (+resid) (+gelu)
// BM=BN=64, BK=16, 256 threads, 4x4 per thread. All dims divide tiles.
// ---------------------------------------------------------------------------
#define EPI_BIAS 0
#define EPI_BIAS_RES 1
#define EPI_BIAS_GELU 2

template<int EPI>
__global__ __launch_bounds__(256) void gemm_kernel(
    const float* __restrict__ A, const float* __restrict__ B,
    const float* __restrict__ bias, const float* __restrict__ resid,
    float* __restrict__ C, int M, int N, int K)
{
    __shared__ float As[16][68];   // [k][m] transposed, padded
    __shared__ float Bs[16][68];   // [k][n], padded (row stride 272B, 16B aligned)

    int tid = threadIdx.x;
    int tx = tid & 15, ty = tid >> 4;
    int row0 = blockIdx.y * 64, col0 = blockIdx.x * 64;

    int ar = tid >> 2;          // 0..63  A-tile row
    int ak = (tid & 3) * 4;     // 0..12  A-tile k offset
    int bk = tid >> 4;          // 0..15  B-tile k row
    int bc = (tid & 15) * 4;    // 0..60  B-tile col offset

    float acc[4][4] = {};

    for (int k0 = 0; k0 < K; k0 += 16) {
        float4 av = *(const float4*)(A + (size_t)(row0 + ar) * K + k0 + ak);
        float4 bv = *(const float4*)(B + (size_t)(k0 + bk) * N + col0 + bc);
        As[ak + 0][ar] = av.x;
        As[ak + 1][ar] = av.y;
        As[ak + 2][ar] = av.z;
        As[ak + 3][ar] = av.w;
        *(float4*)&Bs[bk][bc] = bv;
        __syncthreads();
#pragma unroll
        for (int kk = 0; kk < 16; ++kk) {
            float a0 = As[kk][ty * 4 + 0], a1 = As[kk][ty * 4 + 1];
            float a2 = As[kk][ty * 4 + 2], a3 = As[kk][ty * 4 + 3];
            float b0 = Bs[kk][tx * 4 + 0], b1 = Bs[kk][tx * 4 + 1];
            float b2 = Bs[kk][tx * 4 + 2], b3 = Bs[kk][tx * 4 + 3];
            acc[0][0] += a0 * b0; acc[0][1] += a0 * b1; acc[0][2] += a0 * b2; acc[0][3] += a0 * b3;
            acc[1][0] += a1 * b0; acc[1][1] += a1 * b1; acc[1][2] += a1 * b2; acc[1][3] += a1 * b3;
            acc[2][0] += a2 * b0; acc[2][1] += a2 * b1; acc[2][2] += a2 * b2; acc[2][3] += a2 * b3;
            acc[3][0] += a3 * b0; acc[3][1] += a3 * b1; acc[3][2] += a3 * b2; acc[3][3] += a3 * b3;
        }
        __syncthreads();
    }

#pragma unroll
    for (int i = 0; i < 4; ++i) {
        int row = row0 + ty * 4 + i;
#pragma unroll
        for (int j = 0; j < 4; ++j) {
            int col = col0 + tx * 4 + j;
            float v = acc[i][j] + bias[col];
            if (EPI == EPI_BIAS_RES) v += resid[(size_t)row * N + col];
            if (EPI == EPI_BIAS_GELU) {
                float u = v;
                v = 0.5f * u * (1.0f + tanhf(0.7978845608028654f * (u + 0.044715f * u * u * u)));
            }
            C[(size_t)row * N + col] = v;
        }
    }
}

// ---------------------------------------------------------------------------
// Causal attention, one block per (q-row, head, batch).
// qkv layout: [4096, 2304] with q at col h*64, k at 768+h*64, v at 1536+h*64
// out: attn [4096, 768] at col h*64  (== transpose-back reshape)
// ---------------------------------------------------------------------------
__global__ __launch_bounds__(256) void attn_kernel(
    const float* __restrict__ qkv, float* __restrict__ attn)
{
    int s = blockIdx.x;
    int h = blockIdx.y;
    int b = blockIdx.z;
    int tid = threadIdx.x;

    __shared__ float qrow[64];
    __shared__ float scores[SS];
    __shared__ float red[256];

    const size_t rowbase = (size_t)(b * SS) * 2304;
    const float* qptr = qkv + rowbase + (size_t)s * 2304 + h * 64;
    if (tid < 64) qrow[tid] = qptr[tid];
    __syncthreads();

    const int kmax = s;  // inclusive, causal
    // scores = (q . k) * 1/8
    for (int k = tid; k <= kmax; k += 256) {
        const float* kptr = qkv + rowbase + (size_t)k * 2304 + 768 + h * 64;
        float dot = 0.f;
#pragma unroll
        for (int d = 0; d < 64; ++d) dot += qrow[d] * kptr[d];
        scores[k] = dot * 0.125f;
    }
    __syncthreads();

    // max reduce
    float mx = -1e30f;
    for (int k = tid; k <= kmax; k += 256) mx = fmaxf(mx, scores[k]);
    red[tid] = mx;
    __syncthreads();
    for (int off = 128; off > 0; off >>= 1) {
        if (tid < off) red[tid] = fmaxf(red[tid], red[tid + off]);
        __syncthreads();
    }
    mx = red[0];
    __syncthreads();

    // exp + sum reduce
    float sum = 0.f;
    for (int k = tid; k <= kmax; k += 256) {
        float e = expf(scores[k] - mx);
        scores[k] = e;
        sum += e;
    }
    red[tid] = sum;
    __syncthreads();
    for (int off = 128; off > 0; off >>= 1) {
        if (tid < off) red[tid] += red[tid + off];
        __syncthreads();
    }
    float inv = 1.0f / red[0];
    __syncthreads();

    // out[d] = sum_k p[k] * V[k][d] ; 4 groups of 64 lanes over k
    int g = tid >> 6, d = tid & 63;
    float acc = 0.f;
    for (int k = g; k <= kmax; k += 4) {
        const float* vptr = qkv + rowbase + (size_t)k * 2304 + 1536 + h * 64;
        acc += scores[k] * vptr[d];
    }
    red[tid] = acc;
    __syncthreads();
    if (g == 0) {
        float tot = red[d] + red[64 + d] + red[128 + d] + red[192 + d];
        attn[(size_t)(b * SS + s) * DD + h * 64 + d] = tot * inv;
    }
}

// ---------------------------------------------------------------------------
// LayerNorm over last dim (768). One block per row; in-place safe.
// ---------------------------------------------------------------------------
__global__ __launch_bounds__(256) void ln_kernel(
    const float* __restrict__ in, const float* __restrict__ gam,
    const float* __restrict__ bet, float* __restrict__ out)
{
    int row = blockIdx.x;
    int tid = threadIdx.x;
    const float* p = in + (size_t)row * DD;
    float v0 = p[tid], v1 = p[tid + 256], v2 = p[tid + 512];

    __shared__ float red[256];
    red[tid] = v0 + v1 + v2;
    __syncthreads();
    for (int off = 128; off > 0; off >>= 1) {
        if (tid < off) red[tid] += red[tid + off];
        __syncthreads();
    }
    float mean = red[0] * (1.0f / DD);
    __syncthreads();

    float d0 = v0 - mean, d1 = v1 - mean, d2 = v2 - mean;
    red[tid] = d0 * d0 + d1 * d1 + d2 * d2;
    __syncthreads();
    for (int off = 128; off > 0; off >>= 1) {
        if (tid < off) red[tid] += red[tid + off];
        __syncthreads();
    }
    float rstd = rsqrtf(red[0] * (1.0f / DD) + 1e-5f);

    float* o = out + (size_t)row * DD;
    o[tid]       = gam[tid]       * (d0 * rstd) + bet[tid];
    o[tid + 256] = gam[tid + 256] * (d1 * rstd) + bet[tid + 256];
    o[tid + 512] = gam[tid + 512] * (d2 * rstd) + bet[tid + 512];
}

// ---------------------------------------------------------------------------
extern "C" void kernel_launch(void* const* d_in, const int* in_sizes, int n_in,
                              void* d_out, int out_size, void* d_ws, size_t ws_size,
                              hipStream_t stream)
{
    const int*   tokens = (const int*)d_in[0];
    const float* we     = (const float*)d_in[1];
    const float* wqkv   = (const float*)d_in[2];
    const float* bqkv   = (const float*)d_in[3];
    const float* wproj  = (const float*)d_in[4];
    const float* bproj  = (const float*)d_in[5];
    const float* g1     = (const float*)d_in[6];
    const float* b1     = (const float*)d_in[7];
    const float* wfc    = (const float*)d_in[8];
    const float* bfc    = (const float*)d_in[9];
    const float* wpr    = (const float*)d_in[10];
    const float* bpr    = (const float*)d_in[11];
    const float* g2     = (const float*)d_in[12];
    const float* b2     = (const float*)d_in[13];
    float* out = (float*)d_out;

    // Workspace layout (floats):
    //   x   : 4096*768
    //   n   : 4096*768
    //   buf : 4096*3072 union buffer:
    //     qkv  = buf[0 : 4096*2304]      (live: GEMM1 -> attn)
    //     attnb= buf[4096*2304 : end]    (live: attn  -> GEMM2)
    //     t    = buf[0 : 4096*768]       (live: GEMM2 -> LN1; qkv dead)
    //     m1   = buf[0 : 4096*3072]      (live: GEMM3 -> GEMM4; t/attnb dead)
    float* x   = (float*)d_ws;
    float* n   = x + (size_t)MM * DD;
    float* buf = n + (size_t)MM * DD;
    float* qkv   = buf;
    float* attnb = buf + (size_t)MM * 2304;
    float* t     = buf;
    float* m1    = buf;

    embed_kernel<<<dim3(MM), 256, 0, stream>>>(tokens, we, x);

    for (int l = 0; l < LL; ++l) {
        // QKV projection
        gemm_kernel<EPI_BIAS><<<dim3(2304 / 64, MM / 64), 256, 0, stream>>>(
            x, wqkv + (size_t)l * DD * 2304, bqkv + (size_t)l * 2304,
            nullptr, qkv, MM, 2304, DD);
        // Attention
        attn_kernel<<<dim3(SS, HH, BB), 256, 0, stream>>>(qkv, attnb);
        // Output projection + residual
        gemm_kernel<EPI_BIAS_RES><<<dim3(DD / 64, MM / 64), 256, 0, stream>>>(
            attnb, wproj + (size_t)l * DD * DD, bproj + (size_t)l * DD,
            x, t, MM, DD, DD);
        // LN1
        ln_kernel<<<dim3(MM), 256, 0, stream>>>(t, g1 + (size_t)l * DD,
                                                b1 + (size_t)l * DD, n);
        // FC + GELU
        gemm_kernel<EPI_BIAS_GELU><<<dim3(DFF / 64, MM / 64), 256, 0, stream>>>(
            n, wfc + (size_t)l * DD * DFF, bfc + (size_t)l * DFF,
            nullptr, m1, MM, DFF, DD);
        // FC2 + residual(n)
        gemm_kernel<EPI_BIAS_RES><<<dim3(DD / 64, MM / 64), 256, 0, stream>>>(
            m1, wpr + (size_t)l * DFF * DD, bpr + (size_t)l * DD,
            n, x, MM, DD, DFF);
        // LN2 (in-place on x; last layer writes d_out)
        ln_kernel<<<dim3(MM), 256, 0, stream>>>(x, g2 + (size_t)l * DD,
                                                b2 + (size_t)l * DD,
                                                (l == LL - 1) ? out : x);
    }
}

// Round 2
// 12043.835 us; speedup vs baseline: 2.2089x; 2.2089x over previous
//
#include <hip/hip_runtime.h>
#include <math.h>

// Problem constants
#define BB 8
#define SS 512
#define DD 768
#define HH 12
#define LL 12
#define DHD 64
#define DFF 3072
#define VV 40478
#define MM (BB*SS)   // 4096 rows

// ---------------------------------------------------------------------------
// Embedding: x[b,s,:] = we[tok[b,s],:] + we[V+s,:]
// ---------------------------------------------------------------------------
__global__ __launch_bounds__(256) void embed_kernel(
    const int* __restrict__ tokens, const float* __restrict__ we,
    float* __restrict__ x)
{
    int i = blockIdx.x;          // 0..4095 (b*512+s)
    int s = i & (SS - 1);
    int tok = tokens[i];
    const float* wt = we + (size_t)tok * DD;
    const float* wp = we + (size_t)(VV + s) * DD;
    float* xr = x + (size_t)i * DD;
    for (int d = threadIdx.x; d < DD; d += 256)
        xr[d] = wt[d] + wp[d];
}

// ---------------------------------------------------------------------------
// Tiled fp32 GEMM: C[M,N] = A[M,K] @ B[K,N] + bias (+resid) (+gelu)
// BM=BN=64, BK=16, 256 threads, 4x4 per thread. All dims divide tiles.
// ---------------------------------------------------------------------------
#define EPI_BIAS 0
#define EPI_BIAS_RES 1
#define EPI_BIAS_GELU 2

template<int EPI>
__global__ __launch_bounds__(256) void gemm_kernel(
    const float* __restrict__ A, const float* __restrict__ B,
    const float* __restrict__ bias, const float* __restrict__ resid,
    float* __restrict__ C, int M, int N, int K)
{
    __shared__ float As[16][68];   // [k][m] transposed, padded
    __shared__ float Bs[16][68];   // [k][n], padded

    int tid = threadIdx.x;
    int tx = tid & 15, ty = tid >> 4;
    int row0 = blockIdx.y * 64, col0 = blockIdx.x * 64;

    int ar = tid >> 2;          // 0..63  A-tile row
    int ak = (tid & 3) * 4;     // 0..12  A-tile k offset
    int bk = tid >> 4;          // 0..15  B-tile k row
    int bc = (tid & 15) * 4;    // 0..60  B-tile col offset

    float acc[4][4] = {};

    for (int k0 = 0; k0 < K; k0 += 16) {
        float4 av = *(const float4*)(A + (size_t)(row0 + ar) * K + k0 + ak);
        float4 bv = *(const float4*)(B + (size_t)(k0 + bk) * N + col0 + bc);
        As[ak + 0][ar] = av.x;
        As[ak + 1][ar] = av.y;
        As[ak + 2][ar] = av.z;
        As[ak + 3][ar] = av.w;
        *(float4*)&Bs[bk][bc] = bv;
        __syncthreads();
#pragma unroll
        for (int kk = 0; kk < 16; ++kk) {
            float a0 = As[kk][ty * 4 + 0], a1 = As[kk][ty * 4 + 1];
            float a2 = As[kk][ty * 4 + 2], a3 = As[kk][ty * 4 + 3];
            float b0 = Bs[kk][tx * 4 + 0], b1 = Bs[kk][tx * 4 + 1];
            float b2 = Bs[kk][tx * 4 + 2], b3 = Bs[kk][tx * 4 + 3];
            acc[0][0] += a0 * b0; acc[0][1] += a0 * b1; acc[0][2] += a0 * b2; acc[0][3] += a0 * b3;
            acc[1][0] += a1 * b0; acc[1][1] += a1 * b1; acc[1][2] += a1 * b2; acc[1][3] += a1 * b3;
            acc[2][0] += a2 * b0; acc[2][1] += a2 * b1; acc[2][2] += a2 * b2; acc[2][3] += a2 * b3;
            acc[3][0] += a3 * b0; acc[3][1] += a3 * b1; acc[3][2] += a3 * b2; acc[3][3] += a3 * b3;
        }
        __syncthreads();
    }

#pragma unroll
    for (int i = 0; i < 4; ++i) {
        int row = row0 + ty * 4 + i;
#pragma unroll
        for (int j = 0; j < 4; ++j) {
            int col = col0 + tx * 4 + j;
            float v = acc[i][j] + bias[col];
            if (EPI == EPI_BIAS_RES) v += resid[(size_t)row * N + col];
            if (EPI == EPI_BIAS_GELU) {
                float u = v;
                v = 0.5f * u * (1.0f + tanhf(0.7978845608028654f * (u + 0.044715f * u * u * u)));
            }
            C[(size_t)row * N + col] = v;
        }
    }
}

// ---------------------------------------------------------------------------
// Flash-style causal attention. One block per (q-tile=64, head, batch).
// qkv layout: [4096, 2304]; q at col h*64, k at 768+h*64, v at 1536+h*64.
// out attnb [4096, 768] at col h*64.
// 256 threads; per thread a 4x4 (q x d) output block.
// ---------------------------------------------------------------------------
__global__ __launch_bounds__(256) void attn_kernel(
    const float* __restrict__ qkv, float* __restrict__ attnb)
{
    int qt = 7 - blockIdx.x;     // largest q-tiles (most k-tiles) first
    int h  = blockIdx.y;
    int b  = blockIdx.z;
    int tid = threadIdx.x;
    int tx = tid & 15, ty = tid >> 4;

    __shared__ float Qs [64][68];   // [qi][d], pre-scaled by 1/8
    __shared__ float KsT[64][68];   // [d][kj]  (transposed K tile)
    __shared__ float Vs [64][68];   // [kj][d]
    __shared__ float Ss [64][68];   // [qi][kj] scores -> probs
    __shared__ float mS[64], lS[64], aS[64];

    const size_t rowbase = (size_t)b * SS * 2304;
    const int q0 = qt * 64;

    // --- load Q tile (scaled) ---
    {
        int r  = tid >> 2;
        int c0 = (tid & 3) * 16;
        const float* src = qkv + rowbase + (size_t)(q0 + r) * 2304 + h * 64 + c0;
#pragma unroll
        for (int i = 0; i < 4; ++i) {
            float4 v = *(const float4*)(src + i * 4);
            v.x *= 0.125f; v.y *= 0.125f; v.z *= 0.125f; v.w *= 0.125f;
            *(float4*)&Qs[r][c0 + i * 4] = v;
        }
    }
    if (tid < 64) { mS[tid] = -1e30f; lS[tid] = 0.f; }

    float o[4][4] = {};

    for (int kt = 0; kt <= qt; ++kt) {
        // --- issue K/V global loads into registers ---
        int r  = tid >> 2;
        int c0 = (tid & 3) * 16;
        const float* ksrc = qkv + rowbase + (size_t)(kt * 64 + r) * 2304 + 768  + h * 64 + c0;
        const float* vsrc = qkv + rowbase + (size_t)(kt * 64 + r) * 2304 + 1536 + h * 64 + c0;
        float4 kr[4], vr[4];
#pragma unroll
        for (int i = 0; i < 4; ++i) kr[i] = *(const float4*)(ksrc + i * 4);
#pragma unroll
        for (int i = 0; i < 4; ++i) vr[i] = *(const float4*)(vsrc + i * 4);

        __syncthreads();   // prior iteration done with KsT/Vs/Ss (and Qs writes on iter 0)

        // --- stage K (transposed) and V ---
#pragma unroll
        for (int i = 0; i < 4; ++i) {
            int c = c0 + i * 4;
            KsT[c + 0][r] = kr[i].x;
            KsT[c + 1][r] = kr[i].y;
            KsT[c + 2][r] = kr[i].z;
            KsT[c + 3][r] = kr[i].w;
            *(float4*)&Vs[r][c] = vr[i];
        }
        __syncthreads();

        // --- S = Q . K^T (4x4 per thread) ---
        float s[4][4] = {};
#pragma unroll
        for (int d0 = 0; d0 < 64; d0 += 4) {
            float4 k0v = *(const float4*)&KsT[d0 + 0][tx * 4];
            float4 k1v = *(const float4*)&KsT[d0 + 1][tx * 4];
            float4 k2v = *(const float4*)&KsT[d0 + 2][tx * 4];
            float4 k3v = *(const float4*)&KsT[d0 + 3][tx * 4];
#pragma unroll
            for (int i = 0; i < 4; ++i) {
                float4 qv = *(const float4*)&Qs[ty * 4 + i][d0];
                s[i][0] += qv.x * k0v.x + qv.y * k1v.x + qv.z * k2v.x + qv.w * k3v.x;
                s[i][1] += qv.x * k0v.y + qv.y * k1v.y + qv.z * k2v.y + qv.w * k3v.y;
                s[i][2] += qv.x * k0v.z + qv.y * k1v.z + qv.z * k2v.z + qv.w * k3v.z;
                s[i][3] += qv.x * k0v.w + qv.y * k1v.w + qv.z * k2v.w + qv.w * k3v.w;
            }
        }

        // --- causal mask on the diagonal tile ---
        if (kt == qt) {
#pragma unroll
            for (int i = 0; i < 4; ++i)
#pragma unroll
                for (int j = 0; j < 4; ++j)
                    if (tx * 4 + j > ty * 4 + i) s[i][j] = -1e30f;
        }

        // --- write scores ---
#pragma unroll
        for (int i = 0; i < 4; ++i)
            *(float4*)&Ss[ty * 4 + i][tx * 4] =
                make_float4(s[i][0], s[i][1], s[i][2], s[i][3]);
        __syncthreads();

        // --- online softmax: 4 lanes per row, 16 cols each ---
        {
            int rr  = tid >> 2;
            int sub = tid & 3;
            float4 p0 = *(const float4*)&Ss[rr][sub * 16 + 0];
            float4 p1 = *(const float4*)&Ss[rr][sub * 16 + 4];
            float4 p2 = *(const float4*)&Ss[rr][sub * 16 + 8];
            float4 p3 = *(const float4*)&Ss[rr][sub * 16 + 12];
            float tmax = fmaxf(fmaxf(fmaxf(p0.x, p0.y), fmaxf(p0.z, p0.w)),
                         fmaxf(fmaxf(fmaxf(p1.x, p1.y), fmaxf(p1.z, p1.w)),
                         fmaxf(fmaxf(fmaxf(p2.x, p2.y), fmaxf(p2.z, p2.w)),
                               fmaxf(fmaxf(p3.x, p3.y), fmaxf(p3.z, p3.w)))));
            tmax = fmaxf(tmax, __shfl_xor(tmax, 1));
            tmax = fmaxf(tmax, __shfl_xor(tmax, 2));
            float mold = mS[rr];
            float mnew = fmaxf(mold, tmax);
            p0.x = __expf(p0.x - mnew); p0.y = __expf(p0.y - mnew);
            p0.z = __expf(p0.z - mnew); p0.w = __expf(p0.w - mnew);
            p1.x = __expf(p1.x - mnew); p1.y = __expf(p1.y - mnew);
            p1.z = __expf(p1.z - mnew); p1.w = __expf(p1.w - mnew);
            p2.x = __expf(p2.x - mnew); p2.y = __expf(p2.y - mnew);
            p2.z = __expf(p2.z - mnew); p2.w = __expf(p2.w - mnew);
            p3.x = __expf(p3.x - mnew); p3.y = __expf(p3.y - mnew);
            p3.z = __expf(p3.z - mnew); p3.w = __expf(p3.w - mnew);
            float sum = p0.x + p0.y + p0.z + p0.w + p1.x + p1.y + p1.z + p1.w
                      + p2.x + p2.y + p2.z + p2.w + p3.x + p3.y + p3.z + p3.w;
            sum += __shfl_xor(sum, 1);
            sum += __shfl_xor(sum, 2);
            *(float4*)&Ss[rr][sub * 16 + 0]  = p0;
            *(float4*)&Ss[rr][sub * 16 + 4]  = p1;
            *(float4*)&Ss[rr][sub * 16 + 8]  = p2;
            *(float4*)&Ss[rr][sub * 16 + 12] = p3;
            if (sub == 0) {
                float al = __expf(mold - mnew);
                aS[rr] = al;
                mS[rr] = mnew;
                lS[rr] = lS[rr] * al + sum;
            }
        }
        __syncthreads();

        // --- O = O*alpha + P @ V ---
        {
            float al[4];
#pragma unroll
            for (int i = 0; i < 4; ++i) al[i] = aS[ty * 4 + i];
#pragma unroll
            for (int i = 0; i < 4; ++i)
#pragma unroll
                for (int j = 0; j < 4; ++j) o[i][j] *= al[i];
#pragma unroll
            for (int k0 = 0; k0 < 64; k0 += 4) {
                float4 v0 = *(const float4*)&Vs[k0 + 0][tx * 4];
                float4 v1 = *(const float4*)&Vs[k0 + 1][tx * 4];
                float4 v2 = *(const float4*)&Vs[k0 + 2][tx * 4];
                float4 v3 = *(const float4*)&Vs[k0 + 3][tx * 4];
#pragma unroll
                for (int i = 0; i < 4; ++i) {
                    float4 pv = *(const float4*)&Ss[ty * 4 + i][k0];
                    o[i][0] += pv.x * v0.x + pv.y * v1.x + pv.z * v2.x + pv.w * v3.x;
                    o[i][1] += pv.x * v0.y + pv.y * v1.y + pv.z * v2.y + pv.w * v3.y;
                    o[i][2] += pv.x * v0.z + pv.y * v1.z + pv.z * v2.z + pv.w * v3.z;
                    o[i][3] += pv.x * v0.w + pv.y * v1.w + pv.z * v2.w + pv.w * v3.w;
                }
            }
        }
    }

    // --- final scale by 1/l and write out ---
#pragma unroll
    for (int i = 0; i < 4; ++i) {
        float inv = 1.0f / lS[ty * 4 + i];
        float4 ov = make_float4(o[i][0] * inv, o[i][1] * inv,
                                o[i][2] * inv, o[i][3] * inv);
        *(float4*)(attnb + (size_t)(b * SS + q0 + ty * 4 + i) * DD + h * 64 + tx * 4) = ov;
    }
}

// ---------------------------------------------------------------------------
// LayerNorm over last dim (768). One block per row; in-place safe.
// ---------------------------------------------------------------------------
__global__ __launch_bounds__(256) void ln_kernel(
    const float* __restrict__ in, const float* __restrict__ gam,
    const float* __restrict__ bet, float* __restrict__ out)
{
    int row = blockIdx.x;
    int tid = threadIdx.x;
    const float* p = in + (size_t)row * DD;
    float v0 = p[tid], v1 = p[tid + 256], v2 = p[tid + 512];

    __shared__ float red[256];
    red[tid] = v0 + v1 + v2;
    __syncthreads();
    for (int off = 128; off > 0; off >>= 1) {
        if (tid < off) red[tid] += red[tid + off];
        __syncthreads();
    }
    float mean = red[0] * (1.0f / DD);
    __syncthreads();

    float d0 = v0 - mean, d1 = v1 - mean, d2 = v2 - mean;
    red[tid] = d0 * d0 + d1 * d1 + d2 * d2;
    __syncthreads();
    for (int off = 128; off > 0; off >>= 1) {
        if (tid < off) red[tid] += red[tid + off];
        __syncthreads();
    }
    float rstd = rsqrtf(red[0] * (1.0f / DD) + 1e-5f);

    float* o = out + (size_t)row * DD;
    o[tid]       = gam[tid]       * (d0 * rstd) + bet[tid];
    o[tid + 256] = gam[tid + 256] * (d1 * rstd) + bet[tid + 256];
    o[tid + 512] = gam[tid + 512] * (d2 * rstd) + bet[tid + 512];
}

// ---------------------------------------------------------------------------
extern "C" void kernel_launch(void* const* d_in, const int* in_sizes, int n_in,
                              void* d_out, int out_size, void* d_ws, size_t ws_size,
                              hipStream_t stream)
{
    const int*   tokens = (const int*)d_in[0];
    const float* we     = (const float*)d_in[1];
    const float* wqkv   = (const float*)d_in[2];
    const float* bqkv   = (const float*)d_in[3];
    const float* wproj  = (const float*)d_in[4];
    const float* bproj  = (const float*)d_in[5];
    const float* g1     = (const float*)d_in[6];
    const float* b1     = (const float*)d_in[7];
    const float* wfc    = (const float*)d_in[8];
    const float* bfc    = (const float*)d_in[9];
    const float* wpr    = (const float*)d_in[10];
    const float* bpr    = (const float*)d_in[11];
    const float* g2     = (const float*)d_in[12];
    const float* b2     = (const float*)d_in[13];
    float* out = (float*)d_out;

    // Workspace layout (floats): x, n, buf (union: qkv+attnb / t / m1)
    float* x   = (float*)d_ws;
    float* n   = x + (size_t)MM * DD;
    float* buf = n + (size_t)MM * DD;
    float* qkv   = buf;
    float* attnb = buf + (size_t)MM * 2304;
    float* t     = buf;
    float* m1    = buf;

    embed_kernel<<<dim3(MM), 256, 0, stream>>>(tokens, we, x);

    for (int l = 0; l < LL; ++l) {
        // QKV projection
        gemm_kernel<EPI_BIAS><<<dim3(2304 / 64, MM / 64), 256, 0, stream>>>(
            x, wqkv + (size_t)l * DD * 2304, bqkv + (size_t)l * 2304,
            nullptr, qkv, MM, 2304, DD);
        // Attention (flash-style tiles)
        attn_kernel<<<dim3(SS / 64, HH, BB), 256, 0, stream>>>(qkv, attnb);
        // Output projection + residual
        gemm_kernel<EPI_BIAS_RES><<<dim3(DD / 64, MM / 64), 256, 0, stream>>>(
            attnb, wproj + (size_t)l * DD * DD, bproj + (size_t)l * DD,
            x, t, MM, DD, DD);
        // LN1
        ln_kernel<<<dim3(MM), 256, 0, stream>>>(t, g1 + (size_t)l * DD,
                                                b1 + (size_t)l * DD, n);
        // FC + GELU
        gemm_kernel<EPI_BIAS_GELU><<<dim3(DFF / 64, MM / 64), 256, 0, stream>>>(
            n, wfc + (size_t)l * DD * DFF, bfc + (size_t)l * DFF,
            nullptr, m1, MM, DFF, DD);
        // FC2 + residual(n)
        gemm_kernel<EPI_BIAS_RES><<<dim3(DD / 64, MM / 64), 256, 0, stream>>>(
            m1, wpr + (size_t)l * DFF * DD, bpr + (size_t)l * DD,
            n, x, MM, DD, DFF);
        // LN2 (in-place on x; last layer writes d_out)
        ln_kernel<<<dim3(MM), 256, 0, stream>>>(x, g2 + (size_t)l * DD,
                                                b2 + (size_t)l * DD,
                                                (l == LL - 1) ? out : x);
    }
}

// Round 3
// 5904.923 us; speedup vs baseline: 4.5054x; 2.0396x over previous
//
#include <hip/hip_runtime.h>
#include <math.h>

// Problem constants
#define BB 8
#define SS 512
#define DD 768
#define HH 12
#define LL 12
#define DFF 3072
#define VV 40478
#define MM (BB*SS)   // 4096 rows

typedef _Float16 half8 __attribute__((ext_vector_type(8)));
typedef float floatx4 __attribute__((ext_vector_type(4)));

// ---------------------------------------------------------------------------
// Embedding: x[b,s,:] = we[tok[b,s],:] + we[V+s,:]
// ---------------------------------------------------------------------------
__global__ __launch_bounds__(256) void embed_kernel(
    const int* __restrict__ tokens, const float* __restrict__ we,
    float* __restrict__ x)
{
    int i = blockIdx.x;
    int s = i & (SS - 1);
    int tok = tokens[i];
    const float* wt = we + (size_t)tok * DD;
    const float* wp = we + (size_t)(VV + s) * DD;
    float* xr = x + (size_t)i * DD;
    for (int d = threadIdx.x; d < DD; d += 256)
        xr[d] = wt[d] + wp[d];
}

// ---------------------------------------------------------------------------
// fp16-MFMA GEMM: C[M,N] = A[M,K] @ B[K,N] + bias (+resid) (+gelu), fp32 I/O.
// 128x128 tile, BK=32, 256 threads (4 waves, each 64x64 via 4x4 MFMA tiles).
// LDS holds tiles in FRAGMENT order: [tile16][lane][8 f16] so every fragment
// ds_read_b128 and every staging ds_write_b128 is lane-contiguous (no bank
// conflicts). Staging converts fp32->fp16 in registers.
// ---------------------------------------------------------------------------
#define EPI_BIAS 0
#define EPI_BIAS_RES 1
#define EPI_BIAS_GELU 2

template<int EPI>
__global__ __launch_bounds__(256) void gemm_f16_kernel(
    const float* __restrict__ A, const float* __restrict__ B,
    const float* __restrict__ bias, const float* __restrict__ resid,
    float* __restrict__ C, int M, int N, int K)
{
    __shared__ _Float16 As[4096];   // 8 mt-tiles x 64 lanes x 8
    __shared__ _Float16 Bs[4096];   // 8 nt-tiles x 64 lanes x 8

    const int tid  = threadIdx.x;
    const int lane = tid & 63;
    const int wave = tid >> 6;
    const int row0 = blockIdx.y * 128, col0 = blockIdx.x * 128;

    // A staging: 2 threads per row, 16 k each (4x float4)
    const int am = tid >> 1;           // 0..127
    const int ak = (tid & 1) << 4;     // 0 / 16
    // B staging: 2 k-groups of 16, one column each
    const int bn = tid & 127;          // 0..127
    const int bk = (tid >> 7) << 4;    // 0 / 16

    const float* aptr = A + (size_t)(row0 + am) * K + ak;
    const float* bptr = B + (size_t)bk * N + col0 + bn;

    // LDS write targets (fragment order)
    _Float16* awr0 = &As[((((am >> 4) << 2) + (ak >> 3)) * 16 + (am & 15)) * 8];
    _Float16* awr1 = awr0 + 16 * 8;
    _Float16* bwr0 = &Bs[((((bn >> 4) << 2) + (bk >> 3)) * 16 + (bn & 15)) * 8];
    _Float16* bwr1 = bwr0 + 16 * 8;

    const int wm = (wave >> 1) << 2;   // mt base (0 / 4)
    const int wn = (wave & 1) << 2;    // nt base (0 / 4)

    floatx4 acc[4][4] = {};

    for (int kk = 0; kk < K; kk += 32) {
        float4 a0 = *(const float4*)(aptr + 0);
        float4 a1 = *(const float4*)(aptr + 4);
        float4 a2 = *(const float4*)(aptr + 8);
        float4 a3 = *(const float4*)(aptr + 12);
        float bv[16];
#pragma unroll
        for (int j = 0; j < 16; ++j) bv[j] = bptr[(size_t)j * N];
        aptr += 32;
        bptr += (size_t)32 * N;

        __syncthreads();   // previous iteration's fragment reads complete

        half8 h;
        h[0] = (_Float16)a0.x; h[1] = (_Float16)a0.y; h[2] = (_Float16)a0.z; h[3] = (_Float16)a0.w;
        h[4] = (_Float16)a1.x; h[5] = (_Float16)a1.y; h[6] = (_Float16)a1.z; h[7] = (_Float16)a1.w;
        *(half8*)awr0 = h;
        h[0] = (_Float16)a2.x; h[1] = (_Float16)a2.y; h[2] = (_Float16)a2.z; h[3] = (_Float16)a2.w;
        h[4] = (_Float16)a3.x; h[5] = (_Float16)a3.y; h[6] = (_Float16)a3.z; h[7] = (_Float16)a3.w;
        *(half8*)awr1 = h;
        h[0] = (_Float16)bv[0]; h[1] = (_Float16)bv[1]; h[2] = (_Float16)bv[2]; h[3] = (_Float16)bv[3];
        h[4] = (_Float16)bv[4]; h[5] = (_Float16)bv[5]; h[6] = (_Float16)bv[6]; h[7] = (_Float16)bv[7];
        *(half8*)bwr0 = h;
        h[0] = (_Float16)bv[8];  h[1] = (_Float16)bv[9];  h[2] = (_Float16)bv[10]; h[3] = (_Float16)bv[11];
        h[4] = (_Float16)bv[12]; h[5] = (_Float16)bv[13]; h[6] = (_Float16)bv[14]; h[7] = (_Float16)bv[15];
        *(half8*)bwr1 = h;

        __syncthreads();   // tiles staged

        half8 af[4], bf[4];
#pragma unroll
        for (int i = 0; i < 4; ++i) af[i] = *(half8*)&As[((wm + i) * 64 + lane) * 8];
#pragma unroll
        for (int i = 0; i < 4; ++i) bf[i] = *(half8*)&Bs[((wn + i) * 64 + lane) * 8];
#pragma unroll
        for (int i = 0; i < 4; ++i)
#pragma unroll
            for (int j = 0; j < 4; ++j)
                acc[i][j] = __builtin_amdgcn_mfma_f32_16x16x32_f16(
                    af[i], bf[j], acc[i][j], 0, 0, 0);
    }

    // Epilogue. C/D layout: col = lane&15, row = (lane>>4)*4 + reg.
#pragma unroll
    for (int i = 0; i < 4; ++i) {
        int rowb = row0 + ((wm + i) << 4) + ((lane >> 4) << 2);
#pragma unroll
        for (int j = 0; j < 4; ++j) {
            int col = col0 + ((wn + j) << 4) + (lane & 15);
            float bsv = bias[col];
#pragma unroll
            for (int r = 0; r < 4; ++r) {
                int row = rowb + r;
                float v = acc[i][j][r] + bsv;
                if (EPI == EPI_BIAS_RES) v += resid[(size_t)row * N + col];
                if (EPI == EPI_BIAS_GELU) {
                    float u = v;
                    v = 0.5f * u * (1.0f + tanhf(0.7978845608028654f * (u + 0.044715f * u * u * u)));
                }
                C[(size_t)row * N + col] = v;
            }
        }
    }
}

// ---------------------------------------------------------------------------
// Flash-style causal attention (fp32). One block per (q-tile=64, head, batch).
// ---------------------------------------------------------------------------
__global__ __launch_bounds__(256) void attn_kernel(
    const float* __restrict__ qkv, float* __restrict__ attnb)
{
    int qt = 7 - blockIdx.x;
    int h  = blockIdx.y;
    int b  = blockIdx.z;
    int tid = threadIdx.x;
    int tx = tid & 15, ty = tid >> 4;

    __shared__ float Qs [64][68];
    __shared__ float KsT[64][68];
    __shared__ float Vs [64][68];
    __shared__ float Ss [64][68];
    __shared__ float mS[64], lS[64], aS[64];

    const size_t rowbase = (size_t)b * SS * 2304;
    const int q0 = qt * 64;

    {
        int r  = tid >> 2;
        int c0 = (tid & 3) * 16;
        const float* src = qkv + rowbase + (size_t)(q0 + r) * 2304 + h * 64 + c0;
#pragma unroll
        for (int i = 0; i < 4; ++i) {
            float4 v = *(const float4*)(src + i * 4);
            v.x *= 0.125f; v.y *= 0.125f; v.z *= 0.125f; v.w *= 0.125f;
            *(float4*)&Qs[r][c0 + i * 4] = v;
        }
    }
    if (tid < 64) { mS[tid] = -1e30f; lS[tid] = 0.f; }

    float o[4][4] = {};

    for (int kt = 0; kt <= qt; ++kt) {
        int r  = tid >> 2;
        int c0 = (tid & 3) * 16;
        const float* ksrc = qkv + rowbase + (size_t)(kt * 64 + r) * 2304 + 768  + h * 64 + c0;
        const float* vsrc = qkv + rowbase + (size_t)(kt * 64 + r) * 2304 + 1536 + h * 64 + c0;
        float4 kr[4], vr[4];
#pragma unroll
        for (int i = 0; i < 4; ++i) kr[i] = *(const float4*)(ksrc + i * 4);
#pragma unroll
        for (int i = 0; i < 4; ++i) vr[i] = *(const float4*)(vsrc + i * 4);

        __syncthreads();

#pragma unroll
        for (int i = 0; i < 4; ++i) {
            int c = c0 + i * 4;
            KsT[c + 0][r] = kr[i].x;
            KsT[c + 1][r] = kr[i].y;
            KsT[c + 2][r] = kr[i].z;
            KsT[c + 3][r] = kr[i].w;
            *(float4*)&Vs[r][c] = vr[i];
        }
        __syncthreads();

        float s[4][4] = {};
#pragma unroll
        for (int d0 = 0; d0 < 64; d0 += 4) {
            float4 k0v = *(const float4*)&KsT[d0 + 0][tx * 4];
            float4 k1v = *(const float4*)&KsT[d0 + 1][tx * 4];
            float4 k2v = *(const float4*)&KsT[d0 + 2][tx * 4];
            float4 k3v = *(const float4*)&KsT[d0 + 3][tx * 4];
#pragma unroll
            for (int i = 0; i < 4; ++i) {
                float4 qv = *(const float4*)&Qs[ty * 4 + i][d0];
                s[i][0] += qv.x * k0v.x + qv.y * k1v.x + qv.z * k2v.x + qv.w * k3v.x;
                s[i][1] += qv.x * k0v.y + qv.y * k1v.y + qv.z * k2v.y + qv.w * k3v.y;
                s[i][2] += qv.x * k0v.z + qv.y * k1v.z + qv.z * k2v.z + qv.w * k3v.z;
                s[i][3] += qv.x * k0v.w + qv.y * k1v.w + qv.z * k2v.w + qv.w * k3v.w;
            }
        }

        if (kt == qt) {
#pragma unroll
            for (int i = 0; i < 4; ++i)
#pragma unroll
                for (int j = 0; j < 4; ++j)
                    if (tx * 4 + j > ty * 4 + i) s[i][j] = -1e30f;
        }

#pragma unroll
        for (int i = 0; i < 4; ++i)
            *(float4*)&Ss[ty * 4 + i][tx * 4] =
                make_float4(s[i][0], s[i][1], s[i][2], s[i][3]);
        __syncthreads();

        {
            int rr  = tid >> 2;
            int sub = tid & 3;
            float4 p0 = *(const float4*)&Ss[rr][sub * 16 + 0];
            float4 p1 = *(const float4*)&Ss[rr][sub * 16 + 4];
            float4 p2 = *(const float4*)&Ss[rr][sub * 16 + 8];
            float4 p3 = *(const float4*)&Ss[rr][sub * 16 + 12];
            float tmax = fmaxf(fmaxf(fmaxf(p0.x, p0.y), fmaxf(p0.z, p0.w)),
                         fmaxf(fmaxf(fmaxf(p1.x, p1.y), fmaxf(p1.z, p1.w)),
                         fmaxf(fmaxf(fmaxf(p2.x, p2.y), fmaxf(p2.z, p2.w)),
                               fmaxf(fmaxf(p3.x, p3.y), fmaxf(p3.z, p3.w)))));
            tmax = fmaxf(tmax, __shfl_xor(tmax, 1));
            tmax = fmaxf(tmax, __shfl_xor(tmax, 2));
            float mold = mS[rr];
            float mnew = fmaxf(mold, tmax);
            p0.x = __expf(p0.x - mnew); p0.y = __expf(p0.y - mnew);
            p0.z = __expf(p0.z - mnew); p0.w = __expf(p0.w - mnew);
            p1.x = __expf(p1.x - mnew); p1.y = __expf(p1.y - mnew);
            p1.z = __expf(p1.z - mnew); p1.w = __expf(p1.w - mnew);
            p2.x = __expf(p2.x - mnew); p2.y = __expf(p2.y - mnew);
            p2.z = __expf(p2.z - mnew); p2.w = __expf(p2.w - mnew);
            p3.x = __expf(p3.x - mnew); p3.y = __expf(p3.y - mnew);
            p3.z = __expf(p3.z - mnew); p3.w = __expf(p3.w - mnew);
            float sum = p0.x + p0.y + p0.z + p0.w + p1.x + p1.y + p1.z + p1.w
                      + p2.x + p2.y + p2.z + p2.w + p3.x + p3.y + p3.z + p3.w;
            sum += __shfl_xor(sum, 1);
            sum += __shfl_xor(sum, 2);
            *(float4*)&Ss[rr][sub * 16 + 0]  = p0;
            *(float4*)&Ss[rr][sub * 16 + 4]  = p1;
            *(float4*)&Ss[rr][sub * 16 + 8]  = p2;
            *(float4*)&Ss[rr][sub * 16 + 12] = p3;
            if (sub == 0) {
                float al = __expf(mold - mnew);
                aS[rr] = al;
                mS[rr] = mnew;
                lS[rr] = lS[rr] * al + sum;
            }
        }
        __syncthreads();

        {
            float al[4];
#pragma unroll
            for (int i = 0; i < 4; ++i) al[i] = aS[ty * 4 + i];
#pragma unroll
            for (int i = 0; i < 4; ++i)
#pragma unroll
                for (int j = 0; j < 4; ++j) o[i][j] *= al[i];
#pragma unroll
            for (int k0 = 0; k0 < 64; k0 += 4) {
                float4 v0 = *(const float4*)&Vs[k0 + 0][tx * 4];
                float4 v1 = *(const float4*)&Vs[k0 + 1][tx * 4];
                float4 v2 = *(const float4*)&Vs[k0 + 2][tx * 4];
                float4 v3 = *(const float4*)&Vs[k0 + 3][tx * 4];
#pragma unroll
                for (int i = 0; i < 4; ++i) {
                    float4 pv = *(const float4*)&Ss[ty * 4 + i][k0];
                    o[i][0] += pv.x * v0.x + pv.y * v1.x + pv.z * v2.x + pv.w * v3.x;
                    o[i][1] += pv.x * v0.y + pv.y * v1.y + pv.z * v2.y + pv.w * v3.y;
                    o[i][2] += pv.x * v0.z + pv.y * v1.z + pv.z * v2.z + pv.w * v3.z;
                    o[i][3] += pv.x * v0.w + pv.y * v1.w + pv.z * v2.w + pv.w * v3.w;
                }
            }
        }
    }

#pragma unroll
    for (int i = 0; i < 4; ++i) {
        float inv = 1.0f / lS[ty * 4 + i];
        float4 ov = make_float4(o[i][0] * inv, o[i][1] * inv,
                                o[i][2] * inv, o[i][3] * inv);
        *(float4*)(attnb + (size_t)(b * SS + q0 + ty * 4 + i) * DD + h * 64 + tx * 4) = ov;
    }
}

// ---------------------------------------------------------------------------
// LayerNorm over last dim (768). One block per row; in-place safe.
// ---------------------------------------------------------------------------
__global__ __launch_bounds__(256) void ln_kernel(
    const float* __restrict__ in, const float* __restrict__ gam,
    const float* __restrict__ bet, float* __restrict__ out)
{
    int row = blockIdx.x;
    int tid = threadIdx.x;
    const float* p = in + (size_t)row * DD;
    float v0 = p[tid], v1 = p[tid + 256], v2 = p[tid + 512];

    __shared__ float red[256];
    red[tid] = v0 + v1 + v2;
    __syncthreads();
    for (int off = 128; off > 0; off >>= 1) {
        if (tid < off) red[tid] += red[tid + off];
        __syncthreads();
    }
    float mean = red[0] * (1.0f / DD);
    __syncthreads();

    float d0 = v0 - mean, d1 = v1 - mean, d2 = v2 - mean;
    red[tid] = d0 * d0 + d1 * d1 + d2 * d2;
    __syncthreads();
    for (int off = 128; off > 0; off >>= 1) {
        if (tid < off) red[tid] += red[tid + off];
        __syncthreads();
    }
    float rstd = rsqrtf(red[0] * (1.0f / DD) + 1e-5f);

    float* o = out + (size_t)row * DD;
    o[tid]       = gam[tid]       * (d0 * rstd) + bet[tid];
    o[tid + 256] = gam[tid + 256] * (d1 * rstd) + bet[tid + 256];
    o[tid + 512] = gam[tid + 512] * (d2 * rstd) + bet[tid + 512];
}

// ---------------------------------------------------------------------------
extern "C" void kernel_launch(void* const* d_in, const int* in_sizes, int n_in,
                              void* d_out, int out_size, void* d_ws, size_t ws_size,
                              hipStream_t stream)
{
    const int*   tokens = (const int*)d_in[0];
    const float* we     = (const float*)d_in[1];
    const float* wqkv   = (const float*)d_in[2];
    const float* bqkv   = (const float*)d_in[3];
    const float* wproj  = (const float*)d_in[4];
    const float* bproj  = (const float*)d_in[5];
    const float* g1     = (const float*)d_in[6];
    const float* b1     = (const float*)d_in[7];
    const float* wfc    = (const float*)d_in[8];
    const float* bfc    = (const float*)d_in[9];
    const float* wpr    = (const float*)d_in[10];
    const float* bpr    = (const float*)d_in[11];
    const float* g2     = (const float*)d_in[12];
    const float* b2     = (const float*)d_in[13];
    float* out = (float*)d_out;

    float* x   = (float*)d_ws;
    float* n   = x + (size_t)MM * DD;
    float* buf = n + (size_t)MM * DD;
    float* qkv   = buf;
    float* attnb = buf + (size_t)MM * 2304;
    float* t     = buf;
    float* m1    = buf;

    embed_kernel<<<dim3(MM), 256, 0, stream>>>(tokens, we, x);

    for (int l = 0; l < LL; ++l) {
        // QKV projection
        gemm_f16_kernel<EPI_BIAS><<<dim3(2304 / 128, MM / 128), 256, 0, stream>>>(
            x, wqkv + (size_t)l * DD * 2304, bqkv + (size_t)l * 2304,
            nullptr, qkv, MM, 2304, DD);
        // Attention (flash-style tiles)
        attn_kernel<<<dim3(SS / 64, HH, BB), 256, 0, stream>>>(qkv, attnb);
        // Output projection + residual
        gemm_f16_kernel<EPI_BIAS_RES><<<dim3(DD / 128, MM / 128), 256, 0, stream>>>(
            attnb, wproj + (size_t)l * DD * DD, bproj + (size_t)l * DD,
            x, t, MM, DD, DD);
        // LN1
        ln_kernel<<<dim3(MM), 256, 0, stream>>>(t, g1 + (size_t)l * DD,
                                                b1 + (size_t)l * DD, n);
        // FC + GELU
        gemm_f16_kernel<EPI_BIAS_GELU><<<dim3(DFF / 128, MM / 128), 256, 0, stream>>>(
            n, wfc + (size_t)l * DD * DFF, bfc + (size_t)l * DFF,
            nullptr, m1, MM, DFF, DD);
        // FC2 + residual(n)
        gemm_f16_kernel<EPI_BIAS_RES><<<dim3(DD / 128, MM / 128), 256, 0, stream>>>(
            m1, wpr + (size_t)l * DFF * DD, bpr + (size_t)l * DD,
            n, x, MM, DD, DFF);
        // LN2 (in-place on x; last layer writes d_out)
        ln_kernel<<<dim3(MM), 256, 0, stream>>>(x, g2 + (size_t)l * DD,
                                                b2 + (size_t)l * DD,
                                                (l == LL - 1) ? out : x);
    }
}

// Round 4
// 3874.349 us; speedup vs baseline: 6.8667x; 1.5241x over previous
//
#include <hip/hip_runtime.h>
#include <math.h>

// Problem constants
#define BB 8
#define SS 512
#define DD 768
#define HH 12
#define LL 12
#define DFF 3072
#define VV 40478
#define MM (BB*SS)   // 4096 rows

typedef _Float16 half8 __attribute__((ext_vector_type(8)));
typedef _Float16 half4 __attribute__((ext_vector_type(4)));
typedef float floatx4 __attribute__((ext_vector_type(4)));

// ---------------------------------------------------------------------------
// Embedding: x[b,s,:] = we[tok[b,s],:] + we[V+s,:]
// ---------------------------------------------------------------------------
__global__ __launch_bounds__(256) void embed_kernel(
    const int* __restrict__ tokens, const float* __restrict__ we,
    float* __restrict__ x)
{
    int i = blockIdx.x;
    int s = i & (SS - 1);
    int tok = tokens[i];
    const float* wt = we + (size_t)tok * DD;
    const float* wp = we + (size_t)(VV + s) * DD;
    float* xr = x + (size_t)i * DD;
    for (int d = threadIdx.x; d < DD; d += 256)
        xr[d] = wt[d] + wp[d];
}

// ---------------------------------------------------------------------------
// fp16-MFMA GEMM: 128x128 tile, BK=32, 256 threads (4 waves, 64x64 each).
// LDS in fragment order: [tile16][lane][8 f16]; all LDS traffic b128.
// Epilogues: BIAS_RES (fp32 C=acc+bias+resid), BIAS_GELU, QKV (write fp16
// q16 scaled, k16, and transposed vT16 for attention).
// ---------------------------------------------------------------------------
#define EPI_BIAS_RES 1
#define EPI_BIAS_GELU 2
#define EPI_QKV 3

template<int EPI>
__global__ __launch_bounds__(256) void gemm_f16_kernel(
    const float* __restrict__ A, const float* __restrict__ B,
    const float* __restrict__ bias, const float* __restrict__ resid,
    float* __restrict__ C,
    _Float16* __restrict__ q16o, _Float16* __restrict__ k16o,
    _Float16* __restrict__ vTo,
    int M, int N, int K)
{
    __shared__ _Float16 As[4096];
    __shared__ _Float16 Bs[4096];

    const int tid  = threadIdx.x;
    const int lane = tid & 63;
    const int wave = tid >> 6;
    const int row0 = blockIdx.y * 128, col0 = blockIdx.x * 128;

    const int am = tid >> 1;
    const int ak = (tid & 1) << 4;
    const int bn = tid & 127;
    const int bk = (tid >> 7) << 4;

    const float* aptr = A + (size_t)(row0 + am) * K + ak;
    const float* bptr = B + (size_t)bk * N + col0 + bn;

    _Float16* awr0 = &As[((((am >> 4) << 2) + (ak >> 3)) * 16 + (am & 15)) * 8];
    _Float16* awr1 = awr0 + 16 * 8;
    _Float16* bwr0 = &Bs[((((bn >> 4) << 2) + (bk >> 3)) * 16 + (bn & 15)) * 8];
    _Float16* bwr1 = bwr0 + 16 * 8;

    const int wm = (wave >> 1) << 2;
    const int wn = (wave & 1) << 2;

    floatx4 acc[4][4] = {};

    for (int kk = 0; kk < K; kk += 32) {
        float4 a0 = *(const float4*)(aptr + 0);
        float4 a1 = *(const float4*)(aptr + 4);
        float4 a2 = *(const float4*)(aptr + 8);
        float4 a3 = *(const float4*)(aptr + 12);
        float bv[16];
#pragma unroll
        for (int j = 0; j < 16; ++j) bv[j] = bptr[(size_t)j * N];
        aptr += 32;
        bptr += (size_t)32 * N;

        __syncthreads();

        half8 h;
        h[0] = (_Float16)a0.x; h[1] = (_Float16)a0.y; h[2] = (_Float16)a0.z; h[3] = (_Float16)a0.w;
        h[4] = (_Float16)a1.x; h[5] = (_Float16)a1.y; h[6] = (_Float16)a1.z; h[7] = (_Float16)a1.w;
        *(half8*)awr0 = h;
        h[0] = (_Float16)a2.x; h[1] = (_Float16)a2.y; h[2] = (_Float16)a2.z; h[3] = (_Float16)a2.w;
        h[4] = (_Float16)a3.x; h[5] = (_Float16)a3.y; h[6] = (_Float16)a3.z; h[7] = (_Float16)a3.w;
        *(half8*)awr1 = h;
        h[0] = (_Float16)bv[0]; h[1] = (_Float16)bv[1]; h[2] = (_Float16)bv[2]; h[3] = (_Float16)bv[3];
        h[4] = (_Float16)bv[4]; h[5] = (_Float16)bv[5]; h[6] = (_Float16)bv[6]; h[7] = (_Float16)bv[7];
        *(half8*)bwr0 = h;
        h[0] = (_Float16)bv[8];  h[1] = (_Float16)bv[9];  h[2] = (_Float16)bv[10]; h[3] = (_Float16)bv[11];
        h[4] = (_Float16)bv[12]; h[5] = (_Float16)bv[13]; h[6] = (_Float16)bv[14]; h[7] = (_Float16)bv[15];
        *(half8*)bwr1 = h;

        __syncthreads();

        half8 af[4], bf[4];
#pragma unroll
        for (int i = 0; i < 4; ++i) af[i] = *(half8*)&As[((wm + i) * 64 + lane) * 8];
#pragma unroll
        for (int i = 0; i < 4; ++i) bf[i] = *(half8*)&Bs[((wn + i) * 64 + lane) * 8];
#pragma unroll
        for (int i = 0; i < 4; ++i)
#pragma unroll
            for (int j = 0; j < 4; ++j)
                acc[i][j] = __builtin_amdgcn_mfma_f32_16x16x32_f16(
                    af[i], bf[j], acc[i][j], 0, 0, 0);
    }

    // Epilogue. C/D layout: col = lane&15, row = (lane>>4)*4 + reg.
    if (EPI == EPI_QKV) {
        const int part = col0 / 768;   // 0=q, 1=k, 2=v (tile never spans parts)
#pragma unroll
        for (int i = 0; i < 4; ++i) {
            int rowb = row0 + ((wm + i) << 4) + ((lane >> 4) << 2);
            int bidx = rowb >> 9;
            int s0   = rowb & 511;
#pragma unroll
            for (int j = 0; j < 4; ++j) {
                int col = col0 + ((wn + j) << 4) + (lane & 15);
                float bsv = bias[col];
                int hh = (col >> 6) % 12;
                int dd = col & 63;
                size_t hb = ((size_t)(bidx * 12 + hh)) << 15;  // *512*64
                if (part == 0) {
#pragma unroll
                    for (int r = 0; r < 4; ++r)
                        q16o[hb + (size_t)(s0 + r) * 64 + dd] =
                            (_Float16)((acc[i][j][r] + bsv) * 0.125f);
                } else if (part == 1) {
#pragma unroll
                    for (int r = 0; r < 4; ++r)
                        k16o[hb + (size_t)(s0 + r) * 64 + dd] =
                            (_Float16)(acc[i][j][r] + bsv);
                } else {
                    half4 pk;
#pragma unroll
                    for (int r = 0; r < 4; ++r)
                        pk[r] = (_Float16)(acc[i][j][r] + bsv);
                    *(half4*)&vTo[hb + (size_t)dd * 512 + s0] = pk;
                }
            }
        }
    } else {
#pragma unroll
        for (int i = 0; i < 4; ++i) {
            int rowb = row0 + ((wm + i) << 4) + ((lane >> 4) << 2);
#pragma unroll
            for (int j = 0; j < 4; ++j) {
                int col = col0 + ((wn + j) << 4) + (lane & 15);
                float bsv = bias[col];
#pragma unroll
                for (int r = 0; r < 4; ++r) {
                    int row = rowb + r;
                    float v = acc[i][j][r] + bsv;
                    if (EPI == EPI_BIAS_RES) v += resid[(size_t)row * N + col];
                    if (EPI == EPI_BIAS_GELU) {
                        float u = v;
                        v = 0.5f * u * (1.0f + tanhf(0.7978845608028654f * (u + 0.044715f * u * u * u)));
                    }
                    C[(size_t)row * N + col] = v;
                }
            }
        }
    }
}

// ---------------------------------------------------------------------------
// MFMA flash attention. Block = (q-tile 64, head, batch); 4 waves x 16 q-rows.
// q16 pre-scaled by 1/8. k16: [b,h,s,d]. vT16: [b,h,d,s]. Out fp32 attnb.
// LDS strides padded (72 f16 / 68 f32) -> all b128 patterns conflict-free.
// ---------------------------------------------------------------------------
__global__ __launch_bounds__(256) void attn_kernel(
    const _Float16* __restrict__ q16, const _Float16* __restrict__ k16,
    const _Float16* __restrict__ vT16, float* __restrict__ attnb)
{
    const int qt = 7 - blockIdx.x;   // biggest q-tiles first
    const int h  = blockIdx.y;
    const int b  = blockIdx.z;
    const int tid  = threadIdx.x;
    const int lane = tid & 63;
    const int wave = tid >> 6;
    const int quad = lane >> 4;
    const int l15  = lane & 15;
    const int wq   = wave << 4;      // wave's q-row base in tile

    __shared__ _Float16 Kt[64 * 72];
    __shared__ _Float16 Vt[64 * 72];   // [d][key]
    __shared__ _Float16 Ps[64 * 72];
    __shared__ float    Ss[64 * 68];
    __shared__ float mS[64], lS[64], aS[64];

    const size_t headbase = ((size_t)(b * HH + h)) << 15;   // *512*64
    const int q0 = qt * 64;

    // Q fragments in registers for the whole kernel (A-operand layout)
    half8 qf0, qf1;
    {
        const _Float16* qp = q16 + headbase + (size_t)(q0 + wq + l15) * 64 + quad * 8;
        qf0 = *(const half8*)qp;
        qf1 = *(const half8*)(qp + 32);
    }
    if (tid < 64) { mS[tid] = -1e30f; lS[tid] = 0.f; }

    floatx4 o[4] = {};

    for (int kt = 0; kt <= qt; ++kt) {
        // --- stage K tile [key][d] and V^T tile [d][key] ---
        {
            int r = tid >> 2;
            int c = (tid & 3) << 4;
            const _Float16* kp = k16 + headbase + (size_t)(kt * 64 + r) * 64 + c;
            half8 k0 = *(const half8*)kp;
            half8 k1 = *(const half8*)(kp + 8);
            const _Float16* vp = vT16 + headbase + (size_t)r * 512 + kt * 64 + c;
            half8 v0 = *(const half8*)vp;
            half8 v1 = *(const half8*)(vp + 8);
            __syncthreads();   // previous iteration fully consumed LDS
            *(half8*)&Kt[r * 72 + c]     = k0;
            *(half8*)&Kt[r * 72 + c + 8] = k1;
            *(half8*)&Vt[r * 72 + c]     = v0;
            *(half8*)&Vt[r * 72 + c + 8] = v1;
        }
        __syncthreads();

        // --- S = Q K^T : 4 key-subtiles x 2 MFMA ---
        floatx4 s4[4];
#pragma unroll
        for (int t4 = 0; t4 < 4; ++t4) {
            half8 kf0 = *(const half8*)&Kt[(t4 * 16 + l15) * 72 + quad * 8];
            half8 kf1 = *(const half8*)&Kt[(t4 * 16 + l15) * 72 + quad * 8 + 32];
            floatx4 a = {};
            a = __builtin_amdgcn_mfma_f32_16x16x32_f16(qf0, kf0, a, 0, 0, 0);
            a = __builtin_amdgcn_mfma_f32_16x16x32_f16(qf1, kf1, a, 0, 0, 0);
            s4[t4] = a;
        }

        // --- causal mask on diagonal tile ---
        if (kt == qt) {
#pragma unroll
            for (int t4 = 0; t4 < 4; ++t4) {
                int kc = t4 * 16 + l15;
#pragma unroll
                for (int r = 0; r < 4; ++r)
                    if (kc > wq + quad * 4 + r) s4[t4][r] = -1e30f;
            }
        }

        // --- scores to LDS (C-layout scatter, conflict-free) ---
#pragma unroll
        for (int t4 = 0; t4 < 4; ++t4)
#pragma unroll
            for (int r = 0; r < 4; ++r)
                Ss[(wq + quad * 4 + r) * 68 + t4 * 16 + l15] = s4[t4][r];
        __syncthreads();

        // --- online softmax: 4 lanes per row, 16 cols each ---
        {
            int rr = tid >> 2, sub = tid & 3;
            float4 p0 = *(const float4*)&Ss[rr * 68 + sub * 16 + 0];
            float4 p1 = *(const float4*)&Ss[rr * 68 + sub * 16 + 4];
            float4 p2 = *(const float4*)&Ss[rr * 68 + sub * 16 + 8];
            float4 p3 = *(const float4*)&Ss[rr * 68 + sub * 16 + 12];
            float tmax = fmaxf(fmaxf(fmaxf(p0.x, p0.y), fmaxf(p0.z, p0.w)),
                         fmaxf(fmaxf(fmaxf(p1.x, p1.y), fmaxf(p1.z, p1.w)),
                         fmaxf(fmaxf(fmaxf(p2.x, p2.y), fmaxf(p2.z, p2.w)),
                               fmaxf(fmaxf(p3.x, p3.y), fmaxf(p3.z, p3.w)))));
            tmax = fmaxf(tmax, __shfl_xor(tmax, 1));
            tmax = fmaxf(tmax, __shfl_xor(tmax, 2));
            float mold = mS[rr];
            float mnew = fmaxf(mold, tmax);
            p0.x = __expf(p0.x - mnew); p0.y = __expf(p0.y - mnew);
            p0.z = __expf(p0.z - mnew); p0.w = __expf(p0.w - mnew);
            p1.x = __expf(p1.x - mnew); p1.y = __expf(p1.y - mnew);
            p1.z = __expf(p1.z - mnew); p1.w = __expf(p1.w - mnew);
            p2.x = __expf(p2.x - mnew); p2.y = __expf(p2.y - mnew);
            p2.z = __expf(p2.z - mnew); p2.w = __expf(p2.w - mnew);
            p3.x = __expf(p3.x - mnew); p3.y = __expf(p3.y - mnew);
            p3.z = __expf(p3.z - mnew); p3.w = __expf(p3.w - mnew);
            float sum = p0.x + p0.y + p0.z + p0.w + p1.x + p1.y + p1.z + p1.w
                      + p2.x + p2.y + p2.z + p2.w + p3.x + p3.y + p3.z + p3.w;
            sum += __shfl_xor(sum, 1);
            sum += __shfl_xor(sum, 2);
            half8 ph0, ph1;
            ph0[0] = (_Float16)p0.x; ph0[1] = (_Float16)p0.y;
            ph0[2] = (_Float16)p0.z; ph0[3] = (_Float16)p0.w;
            ph0[4] = (_Float16)p1.x; ph0[5] = (_Float16)p1.y;
            ph0[6] = (_Float16)p1.z; ph0[7] = (_Float16)p1.w;
            ph1[0] = (_Float16)p2.x; ph1[1] = (_Float16)p2.y;
            ph1[2] = (_Float16)p2.z; ph1[3] = (_Float16)p2.w;
            ph1[4] = (_Float16)p3.x; ph1[5] = (_Float16)p3.y;
            ph1[6] = (_Float16)p3.z; ph1[7] = (_Float16)p3.w;
            *(half8*)&Ps[rr * 72 + sub * 16]     = ph0;
            *(half8*)&Ps[rr * 72 + sub * 16 + 8] = ph1;
            if (sub == 0) {
                float al = __expf(mold - mnew);
                aS[rr] = al;
                mS[rr] = mnew;
                lS[rr] = lS[rr] * al + sum;
            }
        }
        __syncthreads();

        // --- O = O*alpha + P @ V ---
        {
            float al[4];
#pragma unroll
            for (int r = 0; r < 4; ++r) al[r] = aS[wq + quad * 4 + r];
#pragma unroll
            for (int dt = 0; dt < 4; ++dt)
#pragma unroll
                for (int r = 0; r < 4; ++r) o[dt][r] *= al[r];

            half8 pf0 = *(const half8*)&Ps[(wq + l15) * 72 + quad * 8];
            half8 pf1 = *(const half8*)&Ps[(wq + l15) * 72 + quad * 8 + 32];
#pragma unroll
            for (int dt = 0; dt < 4; ++dt) {
                half8 vf0 = *(const half8*)&Vt[(dt * 16 + l15) * 72 + quad * 8];
                half8 vf1 = *(const half8*)&Vt[(dt * 16 + l15) * 72 + quad * 8 + 32];
                o[dt] = __builtin_amdgcn_mfma_f32_16x16x32_f16(pf0, vf0, o[dt], 0, 0, 0);
                o[dt] = __builtin_amdgcn_mfma_f32_16x16x32_f16(pf1, vf1, o[dt], 0, 0, 0);
            }
        }
    }

    // --- finalize: O / l, write fp32 [token][768] ---
    float inv[4];
#pragma unroll
    for (int r = 0; r < 4; ++r) inv[r] = 1.0f / lS[wq + quad * 4 + r];
#pragma unroll
    for (int dt = 0; dt < 4; ++dt) {
        int col = h * 64 + dt * 16 + l15;
#pragma unroll
        for (int r = 0; r < 4; ++r) {
            int row = b * SS + q0 + wq + quad * 4 + r;
            attnb[(size_t)row * DD + col] = o[dt][r] * inv[r];
        }
    }
}

// ---------------------------------------------------------------------------
// LayerNorm over last dim (768). One block per row; in-place safe.
// ---------------------------------------------------------------------------
__global__ __launch_bounds__(256) void ln_kernel(
    const float* __restrict__ in, const float* __restrict__ gam,
    const float* __restrict__ bet, float* __restrict__ out)
{
    int row = blockIdx.x;
    int tid = threadIdx.x;
    const float* p = in + (size_t)row * DD;
    float v0 = p[tid], v1 = p[tid + 256], v2 = p[tid + 512];

    __shared__ float red[256];
    red[tid] = v0 + v1 + v2;
    __syncthreads();
    for (int off = 128; off > 0; off >>= 1) {
        if (tid < off) red[tid] += red[tid + off];
        __syncthreads();
    }
    float mean = red[0] * (1.0f / DD);
    __syncthreads();

    float d0 = v0 - mean, d1 = v1 - mean, d2 = v2 - mean;
    red[tid] = d0 * d0 + d1 * d1 + d2 * d2;
    __syncthreads();
    for (int off = 128; off > 0; off >>= 1) {
        if (tid < off) red[tid] += red[tid + off];
        __syncthreads();
    }
    float rstd = rsqrtf(red[0] * (1.0f / DD) + 1e-5f);

    float* o = out + (size_t)row * DD;
    o[tid]       = gam[tid]       * (d0 * rstd) + bet[tid];
    o[tid + 256] = gam[tid + 256] * (d1 * rstd) + bet[tid + 256];
    o[tid + 512] = gam[tid + 512] * (d2 * rstd) + bet[tid + 512];
}

// ---------------------------------------------------------------------------
extern "C" void kernel_launch(void* const* d_in, const int* in_sizes, int n_in,
                              void* d_out, int out_size, void* d_ws, size_t ws_size,
                              hipStream_t stream)
{
    const int*   tokens = (const int*)d_in[0];
    const float* we     = (const float*)d_in[1];
    const float* wqkv   = (const float*)d_in[2];
    const float* bqkv   = (const float*)d_in[3];
    const float* wproj  = (const float*)d_in[4];
    const float* bproj  = (const float*)d_in[5];
    const float* g1     = (const float*)d_in[6];
    const float* b1     = (const float*)d_in[7];
    const float* wfc    = (const float*)d_in[8];
    const float* bfc    = (const float*)d_in[9];
    const float* wpr    = (const float*)d_in[10];
    const float* bpr    = (const float*)d_in[11];
    const float* g2     = (const float*)d_in[12];
    const float* b2     = (const float*)d_in[13];
    float* out = (float*)d_out;

    // Workspace (75.5 MB):
    //   x (12.6M) | n (12.6M) | big (50.3M union):
    //     q16,k16,vT16 (18.9M, QKV->attn) ; attnb (12.6M, attn->proj) ;
    //     t (12.6M, proj->LN1) ; m1 = whole big (FC1->FC2)
    float* x   = (float*)d_ws;
    float* n   = x + (size_t)MM * DD;
    float* big = n + (size_t)MM * DD;
    _Float16* q16  = (_Float16*)big;
    _Float16* k16  = q16 + (size_t)MM * DD;
    _Float16* vT16 = k16 + (size_t)MM * DD;
    float* attnb = (float*)(vT16 + (size_t)MM * DD);
    float* t     = attnb + (size_t)MM * DD;
    float* m1    = big;

    embed_kernel<<<dim3(MM), 256, 0, stream>>>(tokens, we, x);

    for (int l = 0; l < LL; ++l) {
        // QKV projection -> fp16 q/k/vT buffers
        gemm_f16_kernel<EPI_QKV><<<dim3(2304 / 128, MM / 128), 256, 0, stream>>>(
            x, wqkv + (size_t)l * DD * 2304, bqkv + (size_t)l * 2304,
            nullptr, nullptr, q16, k16, vT16, MM, 2304, DD);
        // MFMA flash attention
        attn_kernel<<<dim3(SS / 64, HH, BB), 256, 0, stream>>>(q16, k16, vT16, attnb);
        // Output projection + residual
        gemm_f16_kernel<EPI_BIAS_RES><<<dim3(DD / 128, MM / 128), 256, 0, stream>>>(
            attnb, wproj + (size_t)l * DD * DD, bproj + (size_t)l * DD,
            x, t, nullptr, nullptr, nullptr, MM, DD, DD);
        // LN1
        ln_kernel<<<dim3(MM), 256, 0, stream>>>(t, g1 + (size_t)l * DD,
                                                b1 + (size_t)l * DD, n);
        // FC + GELU
        gemm_f16_kernel<EPI_BIAS_GELU><<<dim3(DFF / 128, MM / 128), 256, 0, stream>>>(
            n, wfc + (size_t)l * DD * DFF, bfc + (size_t)l * DFF,
            nullptr, m1, nullptr, nullptr, nullptr, MM, DFF, DD);
        // FC2 + residual(n)
        gemm_f16_kernel<EPI_BIAS_RES><<<dim3(DD / 128, MM / 128), 256, 0, stream>>>(
            m1, wpr + (size_t)l * DFF * DD, bpr + (size_t)l * DD,
            n, x, nullptr, nullptr, nullptr, MM, DD, DFF);
        // LN2 (in-place on x; last layer writes d_out)
        ln_kernel<<<dim3(MM), 256, 0, stream>>>(x, g2 + (size_t)l * DD,
                                                b2 + (size_t)l * DD,
                                                (l == LL - 1) ? out : x);
    }
}